// Round 6
// baseline (391.956 us; speedup 1.0000x reference)
//
#include <hip/hip_runtime.h>
#include <hip/hip_bf16.h>
#include <stdint.h>

// Problem constants (reference: B,TQ,TK,D,DV = 8,2048,2048,1024,1024)
#define B_  8
#define TQ_ 2048
#define TK_ 2048
#define D_  1024
#define DV_ 1024

typedef __attribute__((ext_vector_type(8))) short  short8;
typedef __attribute__((ext_vector_type(4))) float  floatx4;

__device__ __forceinline__ void async_copy16(const void* g, void* l) {
  // 16B-per-lane global->LDS DMA. LDS dest is wave-uniform base + lane*16.
  __builtin_amdgcn_global_load_lds(
      (const __attribute__((address_space(1))) unsigned int*)g,
      (__attribute__((address_space(3))) unsigned int*)l,
      16, 0, 0);
}

__device__ __forceinline__ ushort f2bf(float f) {
  union { __hip_bfloat16 b; ushort u; } cv;
  cv.b = __float2bfloat16(f);
  return cv.u;
}

__device__ __forceinline__ float bf2f(ushort u) {
  union { ushort u; __hip_bfloat16 b; } cv;
  cv.u = u;
  return __bfloat162float(cv.b);
}

// ---------------- fused prep kernel (unchanged, verified) ----------------
__device__ __forceinline__ void transpose_body(const float* __restrict__ in,
                                               ushort* __restrict__ out,
                                               int R, int C, int r0, int c0,
                                               float (*tile)[65]) {
  const int t = threadIdx.x;
  {
    const int row = t >> 4, col = (t & 15) * 4;
    #pragma unroll
    for (int ro = 0; ro < 4; ro++) {
      const float4 f = *(const float4*)&in[(size_t)(r0 + ro * 16 + row) * C + c0 + col];
      tile[ro * 16 + row][col + 0] = f.x;
      tile[ro * 16 + row][col + 1] = f.y;
      tile[ro * 16 + row][col + 2] = f.z;
      tile[ro * 16 + row][col + 3] = f.w;
    }
  }
  __syncthreads();
  {
    const int c = t >> 4, rg = (t & 15) * 4;
    #pragma unroll
    for (int ro = 0; ro < 4; ro++) {
      const int cc = ro * 16 + c;
      ushort4 o;
      o.x = f2bf(tile[rg + 0][cc]);
      o.y = f2bf(tile[rg + 1][cc]);
      o.z = f2bf(tile[rg + 2][cc]);
      o.w = f2bf(tile[rg + 3][cc]);
      *(ushort4*)&out[(size_t)(c0 + cc) * R + r0 + rg] = o;
    }
  }
}

__global__ void prep(const float* __restrict__ q, const float* __restrict__ k,
                     const float* __restrict__ v, ushort* __restrict__ qb,
                     ushort* __restrict__ ktb, ushort* __restrict__ vtb) {
  __shared__ float tile[64][65];
  const int task = blockIdx.z >> 3;
  const int z    = blockIdx.z & 7;
  if (task == 0) {
    const float4* in  = (const float4*)(q + (size_t)z * TQ_ * D_);
    ushort4*      oup = (ushort4*)(qb + (size_t)z * TQ_ * D_);
    const int i0 = (blockIdx.y * 32 + blockIdx.x) * 1024 + threadIdx.x;
    #pragma unroll
    for (int it = 0; it < 4; it++) {
      const int i = i0 + it * 256;
      float4 f = in[i];
      ushort4 o;
      o.x = f2bf(f.x); o.y = f2bf(f.y); o.z = f2bf(f.z); o.w = f2bf(f.w);
      oup[i] = o;
    }
  } else if (task == 1) {
    transpose_body(k + (size_t)z * D_ * TK_, ktb + (size_t)z * TK_ * D_,
                   D_, TK_, blockIdx.y * 64, blockIdx.x * 64, tile);
  } else {
    transpose_body(v + (size_t)z * TK_ * DV_, vtb + (size_t)z * DV_ * TK_,
                   TK_, DV_, blockIdx.x * 64, blockIdx.y * 64, tile);
  }
}

// ---------------- 128x128-tile high-occupancy GEMM core ----------------
// OCCUPANCY HYPOTHESIS (round 6): all 1-block/CU 256^2 variants (R1-R5)
// were flat at ~380us total with OccupancyPercent ~20% -- 8 waves barrier-
// locked in one phase expose every stall. This core returns to the m97-class
// regime where stall-hiding comes from TLP: 128^2 tile, 256 thr (4 waves,
// 2x2, 64x64/wave = acc[4][4]), BK=32, 32 KiB LDS double-buffer,
// __launch_bounds__(256,4) -> target 4 blocks/CU (4x32=128 KiB LDS <= 160;
// R0 compiled this structure at VGPR 64). While one block sits in its
// __syncthreads/DMA drain, up to 3 other resident blocks compute.
// Per K-step per wave: 16 MFMA + 8 ds_read_b128 + 4 global_load_lds (m97's
// verified instruction mix). Swizzle: the 0-conflict-verified pair from
// R0-R5: read slot (q ^ ((lc>>1)&3)), stage global chunk (t&3)^((t>>3)&3),
// LDS dest linear (DMA requirement). __syncthreads (full drain) accepted by
// design -- TLP covers it.
// LDS layout per 32 KiB block: buf0 A@0 (8KB, 128 rows x 64B), B@8192;
// buf1 A@16384, B@24576.

template <int KDIM>
__device__ __forceinline__ void gemm_core4(const ushort* __restrict__ Ap,
                                           const ushort* __restrict__ Bp,
                                           char* lds, int bm0, int bn0,
                                           floatx4 (&acc)[4][4]) {
  const int t    = threadIdx.x;
  const int lane = t & 63;
  const int w    = t >> 6;
  const int wm   = w >> 1, wn = w & 1;
  const int lc   = lane & 15, q = lane >> 4;
  const int offq = (q ^ ((lc >> 1) & 3)) * 16;   // swizzled 16B slot in 64B row

  const char* Abase = lds + (wm * 64 + lc) * 64 + offq;
  const char* Bbase = lds + 8192 + (wn * 64 + lc) * 64 + offq;

  // hoisted per-thread stage bases: row = t>>2 (0..63), pre-swizzled chunk
  const int srow = t >> 2;
  const int sch  = (t & 3) ^ ((t >> 3) & 3);
  const ushort* gA = Ap + (size_t)(bm0 + srow) * KDIM + sch * 8;
  const ushort* gB = Bp + (size_t)(bn0 + srow) * KDIM + sch * 8;

  #pragma unroll
  for (int mi = 0; mi < 4; ++mi)
    #pragma unroll
    for (int ni = 0; ni < 4; ++ni)
      acc[mi][ni] = (floatx4){0.f, 0.f, 0.f, 0.f};

  // stage one BK=32 tile pair (A 8KB + B 8KB) into buffer at byte ofs bufoff
  auto stage = [&](int bufoff, int k0) {
    char* dA = lds + bufoff + t * 16;
    async_copy16(gA + k0, dA);                       // rows 0..63
    async_copy16(gA + (size_t)64 * KDIM + k0, dA + 4096);  // rows 64..127
    char* dB = lds + 8192 + bufoff + t * 16;
    async_copy16(gB + k0, dB);
    async_copy16(gB + (size_t)64 * KDIM + k0, dB + 4096);
  };

  stage(0, 0);                 // prologue: tile 0 -> buf0
  int cur = 0;                 // byte offset of current buffer: 0 or 16384
  for (int k0 = 0; k0 < KDIM; k0 += 32) {
    __syncthreads();           // drains buf[cur] DMA; releases buf[nxt] readers
    if (k0 + 32 < KDIM) stage(cur ^ 16384, k0 + 32);
    short8 a[4], b[4];
    #pragma unroll
    for (int mi = 0; mi < 4; ++mi)
      a[mi] = *(const short8*)(Abase + cur + mi * 1024);
    #pragma unroll
    for (int ni = 0; ni < 4; ++ni)
      b[ni] = *(const short8*)(Bbase + cur + ni * 1024);
    #pragma unroll
    for (int mi = 0; mi < 4; ++mi)
      #pragma unroll
      for (int ni = 0; ni < 4; ++ni)
        acc[mi][ni] = __builtin_amdgcn_mfma_f32_16x16x32_bf16(a[mi], b[ni],
                                                              acc[mi][ni], 0, 0, 0);
    cur ^= 16384;
  }
}

// XCD-chunked bijective remap (nwg % 8 == 0): each XCD owns one contiguous
// chunk of virtual block ids = exactly one batch for both grids here, so an
// XCD's L2 holds only its own batch's panels. (Verified: FETCH 148->55.7MB.)
__device__ __forceinline__ void xcd_coords(int& bx, int& by, int& bz) {
  const int gx = gridDim.x, gy = gridDim.y;
  int lidx = blockIdx.x + gx * (blockIdx.y + gy * blockIdx.z);
  const int nwg = gx * gy * gridDim.z;
  lidx = (lidx & 7) * (nwg >> 3) + (lidx >> 3);
  bx = lidx % gx;
  const int byz = lidx / gx;
  by = byz % gy;
  bz = byz / gy;
}

// GEMM1: P = exp(tanh(Q K + b)) in bf16; row sums of the bf16-rounded P via
// per-16-lane shuffle reduce + one atomicAdd per row-fragment. (R0 epilogue.)
__global__ __launch_bounds__(256, 4)
void gemm_qk(const ushort* __restrict__ Q, const ushort* __restrict__ Kt,
             const float* __restrict__ bias, ushort* __restrict__ P,
             float* __restrict__ lsum) {
  __shared__ short8 ldsv[2048];        // 32 KiB
  char* lds = (char*)ldsv;
  int bx, by, z;
  xcd_coords(bx, by, z);
  const int bm0 = by * 128;
  const int bn0 = bx * 128;

  floatx4 acc[4][4];
  gemm_core4<D_>(Q + (size_t)z * TQ_ * D_, Kt + (size_t)z * TK_ * D_,
                 lds, bm0, bn0, acc);

  const int lane = threadIdx.x & 63;
  const int w    = threadIdx.x >> 6;
  const int wm   = w >> 1, wn = w & 1;
  const int lc   = lane & 15;
  ushort* Pb = P + (size_t)z * TQ_ * TK_;
  float*  lz = lsum + z * TQ_;

  #pragma unroll
  for (int mi = 0; mi < 4; ++mi) {
    const int grow = bm0 + wm * 64 + mi * 16 + ((lane >> 4) << 2);
    float rs[4] = {0.f, 0.f, 0.f, 0.f};
    #pragma unroll
    for (int ni = 0; ni < 4; ++ni) {
      const int gcol = bn0 + wn * 64 + ni * 16 + lc;
      const float bj = bias[gcol];
      #pragma unroll
      for (int r = 0; r < 4; ++r) {
        float s = acc[mi][ni][r] + bj;
        // tanh(s) = 1 - 2/(e^{2s}+1); safe at +/-inf. exp(tanh) in [0.37,2.72]
        // => softmax needs no max subtraction.
        float tnh = 1.f - 2.f / (__expf(2.f * s) + 1.f);
        float p   = __expf(tnh);
        ushort pu = f2bf(p);
        Pb[(size_t)(grow + r) * TK_ + gcol] = pu;
        rs[r] += bf2f(pu);
      }
    }
    #pragma unroll
    for (int r = 0; r < 4; ++r) {
      rs[r] += __shfl_xor(rs[r], 1, 64);
      rs[r] += __shfl_xor(rs[r], 2, 64);
      rs[r] += __shfl_xor(rs[r], 4, 64);
      rs[r] += __shfl_xor(rs[r], 8, 64);
    }
    if (lc == 0) {
      #pragma unroll
      for (int r = 0; r < 4; ++r) atomicAdd(&lz[grow + r], rs[r]);
    }
  }
}

// GEMM2: out = (P Vt^T) / lsum, fp32 out (R0 epilogue)
__global__ __launch_bounds__(256, 4)
void gemm_pv(const ushort* __restrict__ P, const ushort* __restrict__ Vt,
             const float* __restrict__ lsum, float* __restrict__ out) {
  __shared__ short8 ldsv[2048];        // 32 KiB
  char* lds = (char*)ldsv;
  int bx, by, z;
  xcd_coords(bx, by, z);
  const int bm0 = by * 128;
  const int bn0 = bx * 128;

  floatx4 acc[4][4];
  gemm_core4<TK_>(P + (size_t)z * TQ_ * TK_, Vt + (size_t)z * DV_ * TK_,
                  lds, bm0, bn0, acc);

  const int lane = threadIdx.x & 63;
  const int w    = threadIdx.x >> 6;
  const int wm   = w >> 1, wn = w & 1;
  const int lc   = lane & 15;
  float* ob = out + (size_t)z * TQ_ * DV_;
  const float* lz = lsum + z * TQ_;

  #pragma unroll
  for (int mi = 0; mi < 4; ++mi) {
    const int grow = bm0 + wm * 64 + mi * 16 + ((lane >> 4) << 2);
    float linv[4];
    #pragma unroll
    for (int r = 0; r < 4; ++r) linv[r] = 1.f / lz[grow + r];
    #pragma unroll
    for (int ni = 0; ni < 4; ++ni) {
      const int gcol = bn0 + wn * 64 + ni * 16 + lc;
      #pragma unroll
      for (int r = 0; r < 4; ++r)
        ob[(size_t)(grow + r) * DV_ + gcol] = acc[mi][ni][r] * linv[r];
    }
  }
}

// ---------------- launch ----------------
// Workspace layout (bytes):
//   qb   @ 0         : 8*2048*1024*2 = 33554432   (Q bf16)
//   ktb  @ 33554432  : 33554432                   (K^T bf16, [TK][D])
//   vtb  @ 67108864  : 33554432                   (V^T bf16, [DV][TK])
//   P    @ 100663296 : 8*2048*2048*2 = 67108864   (exp(tanh(S)) bf16)
//   lsum @ 167772160 : 8*2048*4      = 65536      (softmax denominators)
// Total: 167837696 bytes (~160 MB)

extern "C" void kernel_launch(void* const* d_in, const int* in_sizes, int n_in,
                              void* d_out, int out_size, void* d_ws, size_t ws_size,
                              hipStream_t stream) {
  const float* q    = (const float*)d_in[0];
  const float* k    = (const float*)d_in[1];
  const float* v    = (const float*)d_in[2];
  const float* bias = (const float*)d_in[3];
  float* out = (float*)d_out;

  char* ws = (char*)d_ws;
  ushort* qb   = (ushort*)(ws);
  ushort* ktb  = (ushort*)(ws + 33554432);
  ushort* vtb  = (ushort*)(ws + 67108864);
  ushort* P    = (ushort*)(ws + 100663296);
  float*  lsum = (float*)(ws + 167772160);

  hipMemsetAsync(lsum, 0, B_ * TQ_ * sizeof(float), stream);

  prep<<<dim3(32, 16, 24), dim3(256), 0, stream>>>(q, k, v, qb, ktb, vtb);

  gemm_qk<<<dim3(TK_ / 128, TQ_ / 128, B_), dim3(256), 0, stream>>>(qb, ktb, bias, P, lsum);
  gemm_pv<<<dim3(DV_ / 128, TQ_ / 128, B_), dim3(256), 0, stream>>>(P, vtb, lsum, out);
}